// Round 14
// baseline (63.186 us; speedup 1.0000x reference)
//
#include <hip/hip_runtime.h>
#include <cstddef>
#include <stdint.h>

// Problem constants: B=8, Tx=Ty=E=D=256
#define NB 8
#define TX 256
#define TY 256
#define NE 256

// 2*log2(e): tanh(t) = 1 - 2*rcp(1+exp2(CSC*t)).
// Score s = -2 * sum_e v[e] * rcp(1 + Zw[e][x]*Zu[y][e]),
// Zw = exp2(CSC*Ws), Zu = exp2(CSC*Uh); constant sum_e v cancels in softmax.
#define CSC 2.8853900817779268f

__device__ __forceinline__ void gload_lds16(const float* g, float* l) {
    __builtin_amdgcn_global_load_lds(
        (const __attribute__((address_space(1))) void*)g,
        (__attribute__((address_space(3))) void*)l,
        16, 0, 0);
}

// Fused kernel: grid 512 x (64,8).
//   blocks 0..255   = prep role (r13 prep v4 body): 16 rows of Ws (blk<128) or Uh.
//     On completion: release-increment cnt[b]. 32 prep blocks per batch b.
//   blocks 256..511 = attn role (r13 attn v2 body): (b = i&7, y-tile of 8).
//     Entry: acquire-spin until cnt[b]==32.
// Producers never wait -> no deadlock; consumers are the high block ids.
__global__ __launch_bounds__(512) void fused_kernel(
    const float* __restrict__ enc, const float* __restrict__ dec,
    const float* __restrict__ Wa, const float* __restrict__ Ua,
    const float* __restrict__ Va, float* __restrict__ ZwT,
    float* __restrict__ Zu, unsigned int* __restrict__ cnt,
    float* __restrict__ c_out, float* __restrict__ e_out)
{
    __shared__ __align__(16) char smem[82944];
    const int tx = threadIdx.x;            // 0..63
    const int w  = threadIdx.y;            // 0..7
    const int tid = w * 64 + tx;
    int blk = blockIdx.x;

    if (blk < 256) {
        // =================== PREP ROLE ===================
        const bool isU = blk >= 128;
        if (isU) blk -= 128;
        const int b  = blk >> 4;           // 0..7
        const int r0 = (blk & 15) * 16;    // 16 rows per block

        const int rq  = (w & 3) * 4;       // wave's 4 rows
        const int ehh = (w >> 2) * 128;    // wave's e-half
        const int cc  = ehh + tx * 2;      // lane's col pair

        float* rowsT = (float*)smem;       // [256][16] 16 KB
        float* MbL   = rowsT + 4096;       // [2][4096] 32 KB
        float* tL    = MbL + 8192;         // [16][260] 16.6 KB

        const float* M = isU ? Ua : Wa;

        // build rowsT + stage M chunk 0
        const float* src = (isU ? dec : enc) + ((size_t)b * 256 + r0) * NE;
        #pragma unroll
        for (int j = 0; j < 2; ++j) {
            const int f   = tid + j * 512; // 0..1023
            const int row = f & 15;
            const int kq  = f >> 4;        // 0..63
            const float4 v = ((const float4*)src)[row * 64 + kq];
            rowsT[(kq * 4 + 0) * 16 + row] = v.x;
            rowsT[(kq * 4 + 1) * 16 + row] = v.y;
            rowsT[(kq * 4 + 2) * 16 + row] = v.z;
            rowsT[(kq * 4 + 3) * 16 + row] = v.w;
        }
        gload_lds16(M + tid * 4,        MbL + w * 256);
        gload_lds16(M + 2048 + tid * 4, MbL + 2048 + w * 256);
        __syncthreads();

        float2 a0 = make_float2(0.f, 0.f), a1 = a0, a2 = a0, a3 = a0;

        for (int c = 0; c < 16; ++c) {
            if (c < 15) {   // 1-ahead staging; drained by end-of-iter barrier
                const float* g = M + (size_t)(c + 1) * 4096;
                float* dst = MbL + ((c + 1) & 1) * 4096;
                gload_lds16(g + tid * 4,        dst + w * 256);
                gload_lds16(g + 2048 + tid * 4, dst + 2048 + w * 256);
            }
            const float* mb = MbL + (c & 1) * 4096 + cc;
            const int kbase = c * 16;
            #pragma unroll 8
            for (int j = 0; j < 16; ++j) {
                const float2 mw = *(const float2*)(mb + j * 256);
                const float4 rv = *(const float4*)&rowsT[(kbase + j) * 16 + rq];
                a0.x = __builtin_fmaf(rv.x, mw.x, a0.x);
                a0.y = __builtin_fmaf(rv.x, mw.y, a0.y);
                a1.x = __builtin_fmaf(rv.y, mw.x, a1.x);
                a1.y = __builtin_fmaf(rv.y, mw.y, a1.y);
                a2.x = __builtin_fmaf(rv.z, mw.x, a2.x);
                a2.y = __builtin_fmaf(rv.z, mw.y, a2.y);
                a3.x = __builtin_fmaf(rv.w, mw.x, a3.x);
                a3.y = __builtin_fmaf(rv.w, mw.y, a3.y);
            }
            __syncthreads();
        }

        a0.x = __builtin_amdgcn_exp2f(a0.x * CSC);
        a0.y = __builtin_amdgcn_exp2f(a0.y * CSC);
        a1.x = __builtin_amdgcn_exp2f(a1.x * CSC);
        a1.y = __builtin_amdgcn_exp2f(a1.y * CSC);
        a2.x = __builtin_amdgcn_exp2f(a2.x * CSC);
        a2.y = __builtin_amdgcn_exp2f(a2.y * CSC);
        a3.x = __builtin_amdgcn_exp2f(a3.x * CSC);
        a3.y = __builtin_amdgcn_exp2f(a3.y * CSC);

        if (isU) {
            const int rbase = r0 + rq;
            *(float2*)(Zu + ((size_t)b * TY + rbase + 0) * NE + cc) = a0;
            *(float2*)(Zu + ((size_t)b * TY + rbase + 1) * NE + cc) = a1;
            *(float2*)(Zu + ((size_t)b * TY + rbase + 2) * NE + cc) = a2;
            *(float2*)(Zu + ((size_t)b * TY + rbase + 3) * NE + cc) = a3;
        } else {
            tL[(rq + 0) * 260 + cc] = a0.x; tL[(rq + 0) * 260 + cc + 1] = a0.y;
            tL[(rq + 1) * 260 + cc] = a1.x; tL[(rq + 1) * 260 + cc + 1] = a1.y;
            tL[(rq + 2) * 260 + cc] = a2.x; tL[(rq + 2) * 260 + cc + 1] = a2.y;
            tL[(rq + 3) * 260 + cc] = a3.x; tL[(rq + 3) * 260 + cc + 1] = a3.y;
            __syncthreads();
            #pragma unroll
            for (int rep = 0; rep < 2; ++rep) {
                const int f   = tid + rep * 512;
                const int e   = f >> 2;          // 0..255
                const int xq4 = (f & 3) * 4;
                float4 o;
                o.x = tL[(xq4 + 0) * 260 + e];
                o.y = tL[(xq4 + 1) * 260 + e];
                o.z = tL[(xq4 + 2) * 260 + e];
                o.w = tL[(xq4 + 3) * 260 + e];
                *(float4*)(ZwT + ((size_t)b * NE + e) * TX + r0 + xq4) = o;
            }
        }

        __syncthreads();   // all global stores issued & drained (barrier drains vmcnt)
        if (tid == 0)
            __hip_atomic_fetch_add(&cnt[b], 1u, __ATOMIC_RELEASE,
                                   __HIP_MEMORY_SCOPE_AGENT);
        return;
    }

    // =================== ATTN ROLE ===================
    blk -= 256;
    const int b  = blk & 7;                // XCD-affine if rr dispatch
    const int y0 = (blk >> 3) * 8;
    const int y  = y0 + w;

    // wait for batch b's prep (32 producer blocks)
    if (tid == 0) {
        while (__hip_atomic_load(&cnt[b], __ATOMIC_ACQUIRE,
                                 __HIP_MEMORY_SCOPE_AGENT) < 32u)
            __builtin_amdgcn_s_sleep(8);
    }
    __syncthreads();

    float4* zuLo = (float4*)smem;                  // [256] 4 KB
    float4* zuHi = (float4*)(smem + 4096);         // [256] 4 KB
    float*  vL   = (float*)(smem + 8192);          // [256] 1 KB
    float4* accL = (float4*)(smem + 9216);         // [8][8][64] 64 KB
    float*  pLT  = (float*)(smem + 9216 + 65536);  // [8][256] 8 KB
#define ACC(W, Y, T) accL[((W) * 8 + (Y)) * 64 + (T)]

    {
        const int e = tid & 255;
        const float* zp = Zu + ((size_t)b * TY + y0) * NE + e;
        if (tid < 256) {
            zuLo[e] = make_float4(zp[0], zp[NE], zp[2 * NE], zp[3 * NE]);
            vL[e] = Va[e];
        } else {
            zuHi[e] = make_float4(zp[4 * NE], zp[5 * NE], zp[6 * NE], zp[7 * NE]);
        }
    }
    __syncthreads();

    // ---- score: wave e-range [32w, 32w+32), lane x-quad 4tx, 8 y's per load ----
    const float* wp = ZwT + (size_t)b * NE * TX + (size_t)(w * 32) * TX + tx * 4;
    float4 a0 = make_float4(0.f, 0.f, 0.f, 0.f);
    float4 a1 = a0, a2 = a0, a3 = a0, a4 = a0, a5 = a0, a6 = a0, a7 = a0;

#define SC(A, ZU) \
    A.x = __builtin_fmaf(v, __builtin_amdgcn_rcpf(__builtin_fmaf(zw.x, ZU, 1.f)), A.x); \
    A.y = __builtin_fmaf(v, __builtin_amdgcn_rcpf(__builtin_fmaf(zw.y, ZU, 1.f)), A.y); \
    A.z = __builtin_fmaf(v, __builtin_amdgcn_rcpf(__builtin_fmaf(zw.z, ZU, 1.f)), A.z); \
    A.w = __builtin_fmaf(v, __builtin_amdgcn_rcpf(__builtin_fmaf(zw.w, ZU, 1.f)), A.w);

    #pragma unroll 4
    for (int e = 0; e < 32; ++e) {
        const float4 zw = *(const float4*)(wp + (size_t)e * TX);
        const float4 zl = zuLo[w * 32 + e];
        const float4 zh = zuHi[w * 32 + e];
        const float  v  = vL[w * 32 + e];
        SC(a0, zl.x) SC(a1, zl.y) SC(a2, zl.z) SC(a3, zl.w)
        SC(a4, zh.x) SC(a5, zh.y) SC(a6, zh.z) SC(a7, zh.w)
    }
#undef SC
    ACC(w, 0, tx) = a0; ACC(w, 1, tx) = a1;
    ACC(w, 2, tx) = a2; ACC(w, 3, tx) = a3;
    ACC(w, 4, tx) = a4; ACC(w, 5, tx) = a5;
    ACC(w, 6, tx) = a6; ACC(w, 7, tx) = a7;
    __syncthreads();

    // ---- softmax: wave w owns y = y0+w ----
    float4 s = make_float4(0.f, 0.f, 0.f, 0.f);
    #pragma unroll
    for (int ww = 0; ww < 8; ++ww) {
        const float4 a = ACC(ww, w, tx);
        s.x += a.x; s.y += a.y; s.z += a.z; s.w += a.w;
    }
    s.x *= -2.f; s.y *= -2.f; s.z *= -2.f; s.w *= -2.f;

    float m = fmaxf(fmaxf(s.x, s.y), fmaxf(s.z, s.w));
    #pragma unroll
    for (int off = 32; off; off >>= 1) m = fmaxf(m, __shfl_xor(m, off));
    float4 p;
    p.x = __expf(s.x - m);
    p.y = __expf(s.y - m);
    p.z = __expf(s.z - m);
    p.w = __expf(s.w - m);
    float sum = (p.x + p.y) + (p.z + p.w);
    #pragma unroll
    for (int off = 32; off; off >>= 1) sum += __shfl_xor(sum, off);
    const float inv = __builtin_amdgcn_rcpf(sum);
    p.x *= inv; p.y *= inv; p.z *= inv; p.w *= inv;

    *(float4*)(e_out + ((size_t)b * TY + y) * TX + tx * 4) = p;
    *(float4*)&pLT[w * 256 + tx * 4] = p;
    __syncthreads();   // pLT visible; all accL reads (softmax) done

    // ---- context: wave x-range [32w, 32w+32), lane e-quad 4tx, 8 y's ----
    const float* ep = enc + (size_t)b * TX * NE + (size_t)(w * 32) * NE + tx * 4;
    float4 c0 = make_float4(0.f, 0.f, 0.f, 0.f);
    float4 c1 = c0, c2 = c0, c3 = c0, c4 = c0, c5 = c0, c6 = c0, c7 = c0;

#define CTXY(CY, RP, EV) \
    CY.x = __builtin_fmaf(RP, EV.x, CY.x); \
    CY.y = __builtin_fmaf(RP, EV.y, CY.y); \
    CY.z = __builtin_fmaf(RP, EV.z, CY.z); \
    CY.w = __builtin_fmaf(RP, EV.w, CY.w);
#define CTXI(COMP, EV) \
    CTXY(c0, rp0.COMP, EV) CTXY(c1, rp1.COMP, EV) CTXY(c2, rp2.COMP, EV) CTXY(c3, rp3.COMP, EV) \
    CTXY(c4, rp4.COMP, EV) CTXY(c5, rp5.COMP, EV) CTXY(c6, rp6.COMP, EV) CTXY(c7, rp7.COMP, EV)

    #pragma unroll 2
    for (int g = 0; g < 8; ++g) {
        const int xg = g * 4;
        const float4 rp0 = *(const float4*)&pLT[0 * 256 + w * 32 + xg];
        const float4 rp1 = *(const float4*)&pLT[1 * 256 + w * 32 + xg];
        const float4 rp2 = *(const float4*)&pLT[2 * 256 + w * 32 + xg];
        const float4 rp3 = *(const float4*)&pLT[3 * 256 + w * 32 + xg];
        const float4 rp4 = *(const float4*)&pLT[4 * 256 + w * 32 + xg];
        const float4 rp5 = *(const float4*)&pLT[5 * 256 + w * 32 + xg];
        const float4 rp6 = *(const float4*)&pLT[6 * 256 + w * 32 + xg];
        const float4 rp7 = *(const float4*)&pLT[7 * 256 + w * 32 + xg];
        const float4 ev0 = *(const float4*)(ep + (size_t)(xg + 0) * NE);
        const float4 ev1 = *(const float4*)(ep + (size_t)(xg + 1) * NE);
        const float4 ev2 = *(const float4*)(ep + (size_t)(xg + 2) * NE);
        const float4 ev3 = *(const float4*)(ep + (size_t)(xg + 3) * NE);
        CTXI(x, ev0)
        CTXI(y, ev1)
        CTXI(z, ev2)
        CTXI(w, ev3)
    }
#undef CTXI
#undef CTXY

    __syncthreads();   // everyone past pLT reads; safe to overwrite accL
    ACC(w, 0, tx) = c0; ACC(w, 1, tx) = c1;
    ACC(w, 2, tx) = c2; ACC(w, 3, tx) = c3;
    ACC(w, 4, tx) = c4; ACC(w, 5, tx) = c5;
    ACC(w, 6, tx) = c6; ACC(w, 7, tx) = c7;
    __syncthreads();

    float4 cs = make_float4(0.f, 0.f, 0.f, 0.f);
    #pragma unroll
    for (int ww = 0; ww < 8; ++ww) {
        const float4 t = ACC(ww, w, tx);
        cs.x += t.x; cs.y += t.y; cs.z += t.z; cs.w += t.w;
    }
    *(float4*)(c_out + ((size_t)b * TY + y) * NE + tx * 4) = cs;
#undef ACC
}

extern "C" void kernel_launch(void* const* d_in, const int* in_sizes, int n_in,
                              void* d_out, int out_size, void* d_ws, size_t ws_size,
                              hipStream_t stream) {
    const float* enc = (const float*)d_in[0];   // [B,Tx,E]
    const float* dec = (const float*)d_in[1];   // [B,Ty,D]
    const float* Wa  = (const float*)d_in[2];   // [E,E]
    const float* Ua  = (const float*)d_in[3];   // [D,E]
    const float* Va  = (const float*)d_in[4];   // [E,1]

    float* c_out = (float*)d_out;                               // [B,Ty,E]
    float* e_out = (float*)d_out + (size_t)NB * TY * NE;        // [B,Ty,Tx]

    float* ZwT = (float*)d_ws;                                  // [B][E][Tx] 2 MB
    float* Zu  = ZwT + (size_t)NB * NE * TX;                    // [B][Ty][E] 2 MB
    unsigned int* cnt = (unsigned int*)(Zu + (size_t)NB * TY * NE);  // 8 counters

    hipMemsetAsync(cnt, 0, NB * sizeof(unsigned int), stream);
    fused_kernel<<<512, dim3(64, 8), 0, stream>>>(
        enc, dec, Wa, Ua, Va, ZwT, Zu, cnt, c_out, e_out);
}

// Round 15
// 41.671 us; speedup vs baseline: 1.5163x; 1.5163x over previous
//
#include <hip/hip_runtime.h>
#include <cstddef>
#include <stdint.h>

// Problem constants: B=8, Tx=Ty=E=D=256
#define NB 8
#define TX 256
#define TY 256
#define NE 256

// 2*log2(e): tanh(t) = 1 - 2*rcp(1+exp2(CSC*t)).
// Score s = -2 * sum_e v[e] * rcp(1 + Zw[e][x]*Zu[y][e]),
// Zw = exp2(CSC*Ws), Zu = exp2(CSC*Uh); constant sum_e v cancels in softmax.
#define CSC 2.8853900817779268f

__device__ __forceinline__ void gload_lds16(const float* g, float* l) {
    __builtin_amdgcn_global_load_lds(
        (const __attribute__((address_space(1))) void*)g,
        (__attribute__((address_space(3))) void*)l,
        16, 0, 0);
}

// ---------------- prep v4: ZwT[b][e][x] = exp2(CSC*Ws), Zu[b][y][e] = exp2(CSC*Uh)
// Grid 256 x (64,8). blk<128 -> Ws (16 x-rows/block), else Uh (16 y-rows).
// M staged through LDS (16-row chunks, dbuf). Wave w = (row-quad w&3, e-half w>>2);
// lane owns col-PAIR (eh + 2tx). Per k: 1 ds_read_b64 (M) + 1 broadcast b128 (rows)
// -> 8 FMA per 8B LDS-M read (2x the FMA/LDS-byte of the r10 prep).
__global__ __launch_bounds__(512) void prep_kernel(
    const float* __restrict__ enc, const float* __restrict__ dec,
    const float* __restrict__ Wa, const float* __restrict__ Ua,
    float* __restrict__ ZwT, float* __restrict__ Zu)
{
    const int tx = threadIdx.x;           // 0..63
    const int w  = threadIdx.y;           // 0..7
    const int tid = w * 64 + tx;
    int blk = blockIdx.x;
    const bool isU = blk >= 128;
    if (isU) blk -= 128;
    const int b  = blk >> 4;              // 0..7
    const int r0 = (blk & 15) * 16;       // 16 rows per block

    const int rq = (w & 3) * 4;           // wave's 4 rows
    const int eh = (w >> 2) * 128;        // wave's e-half
    const int cc = eh + tx * 2;           // lane's col pair

    __shared__ float rowsT[256][16];      // 16 KB [k][local row] (broadcast reads)
    __shared__ float MbL[2][16 * 256];    // 32 KB M chunk double-buffer
    __shared__ float tL[16][260];         // 16.6 KB transpose buffer (Ws only)

    const float* M = isU ? Ua : Wa;

    // build rowsT + stage M chunk 0
    const float* src = (isU ? dec : enc) + ((size_t)b * 256 + r0) * NE;
    #pragma unroll
    for (int j = 0; j < 2; ++j) {
        const int f   = tid + j * 512;    // 0..1023
        const int row = f & 15;
        const int kq  = f >> 4;           // 0..63
        const float4 v = ((const float4*)src)[row * 64 + kq];
        rowsT[kq * 4 + 0][row] = v.x;
        rowsT[kq * 4 + 1][row] = v.y;
        rowsT[kq * 4 + 2][row] = v.z;
        rowsT[kq * 4 + 3][row] = v.w;
    }
    gload_lds16(M + tid * 4,        MbL[0] + w * 256);
    gload_lds16(M + 2048 + tid * 4, MbL[0] + 2048 + w * 256);
    __syncthreads();

    float2 a0 = make_float2(0.f, 0.f), a1 = a0, a2 = a0, a3 = a0;

    for (int c = 0; c < 16; ++c) {
        if (c < 15) {   // 1-ahead staging; drained by end-of-iter barrier
            const float* g = M + (size_t)(c + 1) * 4096;
            float* dst = MbL[(c + 1) & 1];
            gload_lds16(g + tid * 4,        dst + w * 256);
            gload_lds16(g + 2048 + tid * 4, dst + 2048 + w * 256);
        }
        const float* mb = MbL[c & 1] + cc;
        const int kbase = c * 16;
        #pragma unroll 8
        for (int j = 0; j < 16; ++j) {
            const float2 mw = *(const float2*)(mb + j * 256);
            const float4 rv = *(const float4*)&rowsT[kbase + j][rq];
            a0.x = __builtin_fmaf(rv.x, mw.x, a0.x);
            a0.y = __builtin_fmaf(rv.x, mw.y, a0.y);
            a1.x = __builtin_fmaf(rv.y, mw.x, a1.x);
            a1.y = __builtin_fmaf(rv.y, mw.y, a1.y);
            a2.x = __builtin_fmaf(rv.z, mw.x, a2.x);
            a2.y = __builtin_fmaf(rv.z, mw.y, a2.y);
            a3.x = __builtin_fmaf(rv.w, mw.x, a3.x);
            a3.y = __builtin_fmaf(rv.w, mw.y, a3.y);
        }
        __syncthreads();   // drains own vmcnt -> chunk c+1 landed for all waves
    }

    // fused scale + exp2
    a0.x = __builtin_amdgcn_exp2f(a0.x * CSC);
    a0.y = __builtin_amdgcn_exp2f(a0.y * CSC);
    a1.x = __builtin_amdgcn_exp2f(a1.x * CSC);
    a1.y = __builtin_amdgcn_exp2f(a1.y * CSC);
    a2.x = __builtin_amdgcn_exp2f(a2.x * CSC);
    a2.y = __builtin_amdgcn_exp2f(a2.y * CSC);
    a3.x = __builtin_amdgcn_exp2f(a3.x * CSC);
    a3.y = __builtin_amdgcn_exp2f(a3.y * CSC);

    if (isU) {
        const int rbase = r0 + rq;
        *(float2*)(Zu + ((size_t)b * TY + rbase + 0) * NE + cc) = a0;
        *(float2*)(Zu + ((size_t)b * TY + rbase + 1) * NE + cc) = a1;
        *(float2*)(Zu + ((size_t)b * TY + rbase + 2) * NE + cc) = a2;
        *(float2*)(Zu + ((size_t)b * TY + rbase + 3) * NE + cc) = a3;
    } else {
        tL[rq + 0][cc] = a0.x; tL[rq + 0][cc + 1] = a0.y;
        tL[rq + 1][cc] = a1.x; tL[rq + 1][cc + 1] = a1.y;
        tL[rq + 2][cc] = a2.x; tL[rq + 2][cc + 1] = a2.y;
        tL[rq + 3][cc] = a3.x; tL[rq + 3][cc + 1] = a3.y;
        __syncthreads();
        // transposed store: 1024 float4s (256 e x 4 x-quads), 2 per thread
        #pragma unroll
        for (int rep = 0; rep < 2; ++rep) {
            const int f   = tid + rep * 512;
            const int e   = f >> 2;          // 0..255
            const int xq4 = (f & 3) * 4;
            float4 o;
            o.x = tL[xq4 + 0][e];
            o.y = tL[xq4 + 1][e];
            o.z = tL[xq4 + 2][e];
            o.w = tL[xq4 + 3][e];
            *(float4*)(ZwT + ((size_t)b * NE + e) * TX + r0 + xq4) = o;
        }
    }
}

// ---------------- attn (round 10 champion, verbatim): YT=4, grid 512 ----------------
__global__ __launch_bounds__(512, 4) void attn_kernel(
    const float* __restrict__ enc, const float* __restrict__ ZwT,
    const float* __restrict__ Zu, const float* __restrict__ Va,
    float* __restrict__ c_out, float* __restrict__ e_out)
{
    const int tx = threadIdx.x;            // 0..63
    const int w  = threadIdx.y;            // 0..7
    const int tid = w * 64 + tx;
    const int b  = blockIdx.x & 7;         // XCD-affine if rr dispatch
    const int y0 = (blockIdx.x >> 3) * 4;

    __shared__ float4 zu4L[NE];            // 4 KB: {Zu[y0..y0+3][e]}
    __shared__ float  vL[NE];              // 1 KB
    __shared__ float4 accL[8][4][64];      // 32 KB: per-wave partials (score & ctx)
    __shared__ float  pL4[TX][4];          // 4 KB: p[x][y-local]

    {
        const int e = tid & 255;
        if (tid < 256) {
            const float* zp = Zu + ((size_t)b * TY + y0) * NE + e;
            zu4L[e] = make_float4(zp[0], zp[NE], zp[2 * NE], zp[3 * NE]);
        } else {
            vL[e] = Va[e];
        }
    }
    __syncthreads();

    // ---- score: wave e-range [32w, 32w+32), lane x-quad 4tx, 4 y's per load ----
    const float* wp = ZwT + (size_t)b * NE * TX + (size_t)(w * 32) * TX + tx * 4;
    const float4* zup = &zu4L[w * 32];
    const float*  vp  = &vL[w * 32];
    float4 acc0 = make_float4(0.f, 0.f, 0.f, 0.f);
    float4 acc1 = acc0, acc2 = acc0, acc3 = acc0;
    #pragma unroll 4
    for (int e = 0; e < 32; ++e) {
        const float4 zw  = *(const float4*)(wp + (size_t)e * TX);
        const float4 zu4 = zup[e];
        const float  v   = vp[e];
        acc0.x = __builtin_fmaf(v, __builtin_amdgcn_rcpf(__builtin_fmaf(zw.x, zu4.x, 1.f)), acc0.x);
        acc0.y = __builtin_fmaf(v, __builtin_amdgcn_rcpf(__builtin_fmaf(zw.y, zu4.x, 1.f)), acc0.y);
        acc0.z = __builtin_fmaf(v, __builtin_amdgcn_rcpf(__builtin_fmaf(zw.z, zu4.x, 1.f)), acc0.z);
        acc0.w = __builtin_fmaf(v, __builtin_amdgcn_rcpf(__builtin_fmaf(zw.w, zu4.x, 1.f)), acc0.w);
        acc1.x = __builtin_fmaf(v, __builtin_amdgcn_rcpf(__builtin_fmaf(zw.x, zu4.y, 1.f)), acc1.x);
        acc1.y = __builtin_fmaf(v, __builtin_amdgcn_rcpf(__builtin_fmaf(zw.y, zu4.y, 1.f)), acc1.y);
        acc1.z = __builtin_fmaf(v, __builtin_amdgcn_rcpf(__builtin_fmaf(zw.z, zu4.y, 1.f)), acc1.z);
        acc1.w = __builtin_fmaf(v, __builtin_amdgcn_rcpf(__builtin_fmaf(zw.w, zu4.y, 1.f)), acc1.w);
        acc2.x = __builtin_fmaf(v, __builtin_amdgcn_rcpf(__builtin_fmaf(zw.x, zu4.z, 1.f)), acc2.x);
        acc2.y = __builtin_fmaf(v, __builtin_amdgcn_rcpf(__builtin_fmaf(zw.y, zu4.z, 1.f)), acc2.y);
        acc2.z = __builtin_fmaf(v, __builtin_amdgcn_rcpf(__builtin_fmaf(zw.z, zu4.z, 1.f)), acc2.z);
        acc2.w = __builtin_fmaf(v, __builtin_amdgcn_rcpf(__builtin_fmaf(zw.w, zu4.z, 1.f)), acc2.w);
        acc3.x = __builtin_fmaf(v, __builtin_amdgcn_rcpf(__builtin_fmaf(zw.x, zu4.w, 1.f)), acc3.x);
        acc3.y = __builtin_fmaf(v, __builtin_amdgcn_rcpf(__builtin_fmaf(zw.y, zu4.w, 1.f)), acc3.y);
        acc3.z = __builtin_fmaf(v, __builtin_amdgcn_rcpf(__builtin_fmaf(zw.z, zu4.w, 1.f)), acc3.z);
        acc3.w = __builtin_fmaf(v, __builtin_amdgcn_rcpf(__builtin_fmaf(zw.w, zu4.w, 1.f)), acc3.w);
    }
    accL[w][0][tx] = acc0;
    accL[w][1][tx] = acc1;
    accL[w][2][tx] = acc2;
    accL[w][3][tx] = acc3;
    __syncthreads();

    // ---- softmax: wave w handles y-local = w&3 (waves 4..7 duplicate) ----
    const int yy = w & 3;
    float4 s = make_float4(0.f, 0.f, 0.f, 0.f);
    #pragma unroll
    for (int ww = 0; ww < 8; ++ww) {
        const float4 a = accL[ww][yy][tx];
        s.x += a.x; s.y += a.y; s.z += a.z; s.w += a.w;
    }
    s.x *= -2.f; s.y *= -2.f; s.z *= -2.f; s.w *= -2.f;

    float m = fmaxf(fmaxf(s.x, s.y), fmaxf(s.z, s.w));
    #pragma unroll
    for (int off = 32; off; off >>= 1) m = fmaxf(m, __shfl_xor(m, off));
    float4 p;
    p.x = __expf(s.x - m);
    p.y = __expf(s.y - m);
    p.z = __expf(s.z - m);
    p.w = __expf(s.w - m);
    float sum = (p.x + p.y) + (p.z + p.w);
    #pragma unroll
    for (int off = 32; off; off >>= 1) sum += __shfl_xor(sum, off);
    const float inv = __builtin_amdgcn_rcpf(sum);
    p.x *= inv; p.y *= inv; p.z *= inv; p.w *= inv;

    if (w < 4) {
        *(float4*)(e_out + ((size_t)b * TY + y0 + yy) * TX + tx * 4) = p;
        pL4[tx * 4 + 0][yy] = p.x;
        pL4[tx * 4 + 1][yy] = p.y;
        pL4[tx * 4 + 2][yy] = p.z;
        pL4[tx * 4 + 3][yy] = p.w;
    }
    __syncthreads();

    // ---- context: wave x-range [32w, 32w+32), lane e-quad 4tx, 4 y's per load ----
    const float* ep = enc + (size_t)b * TX * NE + (size_t)(w * 32) * NE + tx * 4;
    float4 c0 = make_float4(0.f, 0.f, 0.f, 0.f);
    float4 c1 = c0, c2 = c0, c3 = c0;
    #pragma unroll 4
    for (int x = 0; x < 32; ++x) {
        const float4 ev = *(const float4*)(ep + (size_t)x * NE);
        const float4 p4 = *(const float4*)&pL4[w * 32 + x][0];
        c0.x = __builtin_fmaf(p4.x, ev.x, c0.x);
        c0.y = __builtin_fmaf(p4.x, ev.y, c0.y);
        c0.z = __builtin_fmaf(p4.x, ev.z, c0.z);
        c0.w = __builtin_fmaf(p4.x, ev.w, c0.w);
        c1.x = __builtin_fmaf(p4.y, ev.x, c1.x);
        c1.y = __builtin_fmaf(p4.y, ev.y, c1.y);
        c1.z = __builtin_fmaf(p4.y, ev.z, c1.z);
        c1.w = __builtin_fmaf(p4.y, ev.w, c1.w);
        c2.x = __builtin_fmaf(p4.z, ev.x, c2.x);
        c2.y = __builtin_fmaf(p4.z, ev.y, c2.y);
        c2.z = __builtin_fmaf(p4.z, ev.z, c2.z);
        c2.w = __builtin_fmaf(p4.z, ev.w, c2.w);
        c3.x = __builtin_fmaf(p4.w, ev.x, c3.x);
        c3.y = __builtin_fmaf(p4.w, ev.y, c3.y);
        c3.z = __builtin_fmaf(p4.w, ev.z, c3.z);
        c3.w = __builtin_fmaf(p4.w, ev.w, c3.w);
    }
    __syncthreads();   // accL reads (softmax) done; safe to overwrite
    accL[w][0][tx] = c0;
    accL[w][1][tx] = c1;
    accL[w][2][tx] = c2;
    accL[w][3][tx] = c3;
    __syncthreads();

    if (w < 4) {
        float4 cs = make_float4(0.f, 0.f, 0.f, 0.f);
        #pragma unroll
        for (int ww = 0; ww < 8; ++ww) {
            const float4 t = accL[ww][w][tx];
            cs.x += t.x; cs.y += t.y; cs.z += t.z; cs.w += t.w;
        }
        *(float4*)(c_out + ((size_t)b * TY + y0 + w) * NE + tx * 4) = cs;
    }
}

extern "C" void kernel_launch(void* const* d_in, const int* in_sizes, int n_in,
                              void* d_out, int out_size, void* d_ws, size_t ws_size,
                              hipStream_t stream) {
    const float* enc = (const float*)d_in[0];   // [B,Tx,E]
    const float* dec = (const float*)d_in[1];   // [B,Ty,D]
    const float* Wa  = (const float*)d_in[2];   // [E,E]
    const float* Ua  = (const float*)d_in[3];   // [D,E]
    const float* Va  = (const float*)d_in[4];   // [E,1]

    float* c_out = (float*)d_out;                               // [B,Ty,E]
    float* e_out = (float*)d_out + (size_t)NB * TY * NE;        // [B,Ty,Tx]

    float* ZwT = (float*)d_ws;                                  // [B][E][Tx]
    float* Zu  = (float*)d_ws + (size_t)NB * NE * TX;           // [B][Ty][E]

    prep_kernel<<<256, dim3(64, 8), 0, stream>>>(enc, dec, Wa, Ua, ZwT, Zu);
    attn_kernel<<<512, dim3(64, 8), 0, stream>>>(enc, ZwT, Zu, Va, c_out, e_out);
}

// Round 16
// 39.584 us; speedup vs baseline: 1.5963x; 1.0527x over previous
//
#include <hip/hip_runtime.h>
#include <cstddef>
#include <stdint.h>

// Problem constants: B=8, Tx=Ty=E=D=256
#define NB 8
#define TX 256
#define TY 256
#define NE 256

// 2*log2(e): tanh(t) = 1 - 2*rcp(1+exp2(CSC*t)).
// Score s = -2 * sum_e v[e] * rcp(1 + Zw[e][x]*Zu[y][e]),
// Zw = exp2(CSC*Ws), Zu = exp2(CSC*Uh); constant sum_e v cancels in softmax.
#define CSC 2.8853900817779268f

__device__ __forceinline__ void gload_lds16(const float* g, float* l) {
    __builtin_amdgcn_global_load_lds(
        (const __attribute__((address_space(1))) void*)g,
        (__attribute__((address_space(3))) void*)l,
        16, 0, 0);
}

// ---------------- prep (round-10 champion): ZwT = exp2(CSC*Ws)^T, Zu = exp2(CSC*Uh)
// Grid 256 x (64,8). blk<128 -> Ws (16 x-rows/block), else Uh (16 y-rows/block).
// M staged through LDS in 16-row chunks (16 KB, double-buffered, global_load_lds),
// shared by all 8 waves. Wave w computes rows {2w,2w+1}; lane owns col-quad 4tx.
__global__ __launch_bounds__(512) void prep_kernel(
    const float* __restrict__ enc, const float* __restrict__ dec,
    const float* __restrict__ Wa, const float* __restrict__ Ua,
    float* __restrict__ ZwT, float* __restrict__ Zu)
{
    const int tx = threadIdx.x;           // 0..63
    const int w  = threadIdx.y;           // 0..7
    const int tid = w * 64 + tx;
    int blk = blockIdx.x;
    const bool isU = blk >= 128;
    if (isU) blk -= 128;
    const int b  = blk >> 4;              // 0..7
    const int r0 = (blk & 15) * 16;       // 16 rows per block

    __shared__ float rowsL[16 * NE];      // 16 KB input rows
    __shared__ float MbL[2][16 * NE];     // 32 KB M chunk double-buffer
    __shared__ float tL[16][260];         // 16.6 KB transpose buffer (Ws only)

    const float* M = isU ? Ua : Wa;

    // stage M chunk 0 (async) + input rows (plain), one barrier
    gload_lds16(M + tid * 4,        MbL[0] + w * 256);
    gload_lds16(M + 2048 + tid * 4, MbL[0] + 2048 + w * 256);
    const float* src = (isU ? dec : enc) + ((size_t)b * 256 + r0) * NE;
    ((float4*)rowsL)[tid]       = ((const float4*)src)[tid];
    ((float4*)rowsL)[tid + 512] = ((const float4*)src)[tid + 512];
    __syncthreads();

    const int e0 = tx * 4;
    const int rA = w * 2, rB = w * 2 + 1;
    float4 acc0 = make_float4(0.f, 0.f, 0.f, 0.f);
    float4 acc1 = make_float4(0.f, 0.f, 0.f, 0.f);
    const float* rowA = rowsL + rA * NE;
    const float* rowB = rowsL + rB * NE;

    for (int c = 0; c < 16; ++c) {
        if (c < 15) {   // issue next chunk early; drained by the end-of-iter barrier
            const float* g = M + (size_t)(c + 1) * 4096;
            float* dst = MbL[(c + 1) & 1];
            gload_lds16(g + tid * 4,        dst + w * 256);
            gload_lds16(g + 2048 + tid * 4, dst + 2048 + w * 256);
        }
        const float* mb = MbL[c & 1] + e0;
        const int kbase = c * 16;
        #pragma unroll
        for (int j = 0; j < 16; ++j) {
            const float4 mw = *(const float4*)(mb + j * 256);
            const float a = rowA[kbase + j];
            const float d = rowB[kbase + j];
            acc0.x = __builtin_fmaf(a, mw.x, acc0.x);
            acc0.y = __builtin_fmaf(a, mw.y, acc0.y);
            acc0.z = __builtin_fmaf(a, mw.z, acc0.z);
            acc0.w = __builtin_fmaf(a, mw.w, acc0.w);
            acc1.x = __builtin_fmaf(d, mw.x, acc1.x);
            acc1.y = __builtin_fmaf(d, mw.y, acc1.y);
            acc1.z = __builtin_fmaf(d, mw.z, acc1.z);
            acc1.w = __builtin_fmaf(d, mw.w, acc1.w);
        }
        __syncthreads();   // drains own vmcnt -> chunk c+1 landed for all waves
    }

    // fused scale + exp2
    acc0.x = __builtin_amdgcn_exp2f(acc0.x * CSC);
    acc0.y = __builtin_amdgcn_exp2f(acc0.y * CSC);
    acc0.z = __builtin_amdgcn_exp2f(acc0.z * CSC);
    acc0.w = __builtin_amdgcn_exp2f(acc0.w * CSC);
    acc1.x = __builtin_amdgcn_exp2f(acc1.x * CSC);
    acc1.y = __builtin_amdgcn_exp2f(acc1.y * CSC);
    acc1.z = __builtin_amdgcn_exp2f(acc1.z * CSC);
    acc1.w = __builtin_amdgcn_exp2f(acc1.w * CSC);

    if (isU) {
        *(float4*)(Zu + ((size_t)b * TY + r0 + rA) * NE + e0) = acc0;
        *(float4*)(Zu + ((size_t)b * TY + r0 + rB) * NE + e0) = acc1;
    } else {
        *(float4*)&tL[rA][e0] = acc0;
        *(float4*)&tL[rB][e0] = acc1;
        __syncthreads();
        // transposed store: 1024 float4s (256 e x 4 xq), 2 per thread
        #pragma unroll
        for (int rep = 0; rep < 2; ++rep) {
            const int f4id = tid + rep * 512;
            const int e  = f4id >> 2;
            const int xq = (f4id & 3) * 4;
            float4 o;
            o.x = tL[xq + 0][e];
            o.y = tL[xq + 1][e];
            o.z = tL[xq + 2][e];
            o.w = tL[xq + 3][e];
            *(float4*)(ZwT + ((size_t)b * NE + e) * TX + r0 + xq) = o;
        }
    }
}

// ---------------- attn (round-10 champion): YT=4, grid 512 ----------------
// Score: wave w owns e-eighth [32w,32w+32); lane tx owns x-quad [4tx,4tx+4);
//   each zw load amortized over ALL 4 y's (zu4 = one LDS b128 broadcast).
// Softmax: 8-partial LDS combine; wave w handles y=w&3 (waves 4..7 duplicate).
// Context: wave w owns x-eighth [32w,32w+32); lane owns e-quad 4tx; all 4 y's.
__global__ __launch_bounds__(512, 4) void attn_kernel(
    const float* __restrict__ enc, const float* __restrict__ ZwT,
    const float* __restrict__ Zu, const float* __restrict__ Va,
    float* __restrict__ c_out, float* __restrict__ e_out)
{
    const int tx = threadIdx.x;            // 0..63
    const int w  = threadIdx.y;            // 0..7
    const int tid = w * 64 + tx;
    const int b  = blockIdx.x & 7;         // XCD-affine if rr dispatch
    const int y0 = (blockIdx.x >> 3) * 4;

    __shared__ float4 zu4L[NE];            // 4 KB: {Zu[y0..y0+3][e]}
    __shared__ float  vL[NE];              // 1 KB
    __shared__ float4 accL[8][4][64];      // 32 KB: per-wave partials (score & ctx)
    __shared__ float  pL4[TX][4];          // 4 KB: p[x][y-local]

    {
        const int e = tid & 255;
        if (tid < 256) {
            const float* zp = Zu + ((size_t)b * TY + y0) * NE + e;
            zu4L[e] = make_float4(zp[0], zp[NE], zp[2 * NE], zp[3 * NE]);
        } else {
            vL[e] = Va[e];
        }
    }
    __syncthreads();

    // ---- score: wave e-range [32w, 32w+32), lane x-quad 4tx, 4 y's per load ----
    const float* wp = ZwT + (size_t)b * NE * TX + (size_t)(w * 32) * TX + tx * 4;
    const float4* zup = &zu4L[w * 32];
    const float*  vp  = &vL[w * 32];
    float4 acc0 = make_float4(0.f, 0.f, 0.f, 0.f);
    float4 acc1 = acc0, acc2 = acc0, acc3 = acc0;
    #pragma unroll 4
    for (int e = 0; e < 32; ++e) {
        const float4 zw  = *(const float4*)(wp + (size_t)e * TX);
        const float4 zu4 = zup[e];
        const float  v   = vp[e];
        acc0.x = __builtin_fmaf(v, __builtin_amdgcn_rcpf(__builtin_fmaf(zw.x, zu4.x, 1.f)), acc0.x);
        acc0.y = __builtin_fmaf(v, __builtin_amdgcn_rcpf(__builtin_fmaf(zw.y, zu4.x, 1.f)), acc0.y);
        acc0.z = __builtin_fmaf(v, __builtin_amdgcn_rcpf(__builtin_fmaf(zw.z, zu4.x, 1.f)), acc0.z);
        acc0.w = __builtin_fmaf(v, __builtin_amdgcn_rcpf(__builtin_fmaf(zw.w, zu4.x, 1.f)), acc0.w);
        acc1.x = __builtin_fmaf(v, __builtin_amdgcn_rcpf(__builtin_fmaf(zw.x, zu4.y, 1.f)), acc1.x);
        acc1.y = __builtin_fmaf(v, __builtin_amdgcn_rcpf(__builtin_fmaf(zw.y, zu4.y, 1.f)), acc1.y);
        acc1.z = __builtin_fmaf(v, __builtin_amdgcn_rcpf(__builtin_fmaf(zw.z, zu4.y, 1.f)), acc1.z);
        acc1.w = __builtin_fmaf(v, __builtin_amdgcn_rcpf(__builtin_fmaf(zw.w, zu4.y, 1.f)), acc1.w);
        acc2.x = __builtin_fmaf(v, __builtin_amdgcn_rcpf(__builtin_fmaf(zw.x, zu4.z, 1.f)), acc2.x);
        acc2.y = __builtin_fmaf(v, __builtin_amdgcn_rcpf(__builtin_fmaf(zw.y, zu4.z, 1.f)), acc2.y);
        acc2.z = __builtin_fmaf(v, __builtin_amdgcn_rcpf(__builtin_fmaf(zw.z, zu4.z, 1.f)), acc2.z);
        acc2.w = __builtin_fmaf(v, __builtin_amdgcn_rcpf(__builtin_fmaf(zw.w, zu4.z, 1.f)), acc2.w);
        acc3.x = __builtin_fmaf(v, __builtin_amdgcn_rcpf(__builtin_fmaf(zw.x, zu4.w, 1.f)), acc3.x);
        acc3.y = __builtin_fmaf(v, __builtin_amdgcn_rcpf(__builtin_fmaf(zw.y, zu4.w, 1.f)), acc3.y);
        acc3.z = __builtin_fmaf(v, __builtin_amdgcn_rcpf(__builtin_fmaf(zw.z, zu4.w, 1.f)), acc3.z);
        acc3.w = __builtin_fmaf(v, __builtin_amdgcn_rcpf(__builtin_fmaf(zw.w, zu4.w, 1.f)), acc3.w);
    }
    accL[w][0][tx] = acc0;
    accL[w][1][tx] = acc1;
    accL[w][2][tx] = acc2;
    accL[w][3][tx] = acc3;
    __syncthreads();

    // ---- softmax: wave w handles y-local = w&3 (waves 4..7 duplicate) ----
    const int yy = w & 3;
    float4 s = make_float4(0.f, 0.f, 0.f, 0.f);
    #pragma unroll
    for (int ww = 0; ww < 8; ++ww) {
        const float4 a = accL[ww][yy][tx];
        s.x += a.x; s.y += a.y; s.z += a.z; s.w += a.w;
    }
    s.x *= -2.f; s.y *= -2.f; s.z *= -2.f; s.w *= -2.f;

    float m = fmaxf(fmaxf(s.x, s.y), fmaxf(s.z, s.w));
    #pragma unroll
    for (int off = 32; off; off >>= 1) m = fmaxf(m, __shfl_xor(m, off));
    float4 p;
    p.x = __expf(s.x - m);
    p.y = __expf(s.y - m);
    p.z = __expf(s.z - m);
    p.w = __expf(s.w - m);
    float sum = (p.x + p.y) + (p.z + p.w);
    #pragma unroll
    for (int off = 32; off; off >>= 1) sum += __shfl_xor(sum, off);
    const float inv = __builtin_amdgcn_rcpf(sum);
    p.x *= inv; p.y *= inv; p.z *= inv; p.w *= inv;

    if (w < 4) {
        *(float4*)(e_out + ((size_t)b * TY + y0 + yy) * TX + tx * 4) = p;
        pL4[tx * 4 + 0][yy] = p.x;
        pL4[tx * 4 + 1][yy] = p.y;
        pL4[tx * 4 + 2][yy] = p.z;
        pL4[tx * 4 + 3][yy] = p.w;
    }
    __syncthreads();

    // ---- context: wave x-range [32w, 32w+32), lane e-quad 4tx, 4 y's per load ----
    const float* ep = enc + (size_t)b * TX * NE + (size_t)(w * 32) * NE + tx * 4;
    float4 c0 = make_float4(0.f, 0.f, 0.f, 0.f);
    float4 c1 = c0, c2 = c0, c3 = c0;
    #pragma unroll 4
    for (int x = 0; x < 32; ++x) {
        const float4 ev = *(const float4*)(ep + (size_t)x * NE);
        const float4 p4 = *(const float4*)&pL4[w * 32 + x][0];
        c0.x = __builtin_fmaf(p4.x, ev.x, c0.x);
        c0.y = __builtin_fmaf(p4.x, ev.y, c0.y);
        c0.z = __builtin_fmaf(p4.x, ev.z, c0.z);
        c0.w = __builtin_fmaf(p4.x, ev.w, c0.w);
        c1.x = __builtin_fmaf(p4.y, ev.x, c1.x);
        c1.y = __builtin_fmaf(p4.y, ev.y, c1.y);
        c1.z = __builtin_fmaf(p4.y, ev.z, c1.z);
        c1.w = __builtin_fmaf(p4.y, ev.w, c1.w);
        c2.x = __builtin_fmaf(p4.z, ev.x, c2.x);
        c2.y = __builtin_fmaf(p4.z, ev.y, c2.y);
        c2.z = __builtin_fmaf(p4.z, ev.z, c2.z);
        c2.w = __builtin_fmaf(p4.z, ev.w, c2.w);
        c3.x = __builtin_fmaf(p4.w, ev.x, c3.x);
        c3.y = __builtin_fmaf(p4.w, ev.y, c3.y);
        c3.z = __builtin_fmaf(p4.w, ev.z, c3.z);
        c3.w = __builtin_fmaf(p4.w, ev.w, c3.w);
    }
    __syncthreads();   // accL reads (softmax) done; safe to overwrite
    accL[w][0][tx] = c0;
    accL[w][1][tx] = c1;
    accL[w][2][tx] = c2;
    accL[w][3][tx] = c3;
    __syncthreads();

    if (w < 4) {
        float4 cs = make_float4(0.f, 0.f, 0.f, 0.f);
        #pragma unroll
        for (int ww = 0; ww < 8; ++ww) {
            const float4 t = accL[ww][w][tx];
            cs.x += t.x; cs.y += t.y; cs.z += t.z; cs.w += t.w;
        }
        *(float4*)(c_out + ((size_t)b * TY + y0 + w) * NE + tx * 4) = cs;
    }
}

extern "C" void kernel_launch(void* const* d_in, const int* in_sizes, int n_in,
                              void* d_out, int out_size, void* d_ws, size_t ws_size,
                              hipStream_t stream) {
    const float* enc = (const float*)d_in[0];   // [B,Tx,E]
    const float* dec = (const float*)d_in[1];   // [B,Ty,D]
    const float* Wa  = (const float*)d_in[2];   // [E,E]
    const float* Ua  = (const float*)d_in[3];   // [D,E]
    const float* Va  = (const float*)d_in[4];   // [E,1]

    float* c_out = (float*)d_out;                               // [B,Ty,E]
    float* e_out = (float*)d_out + (size_t)NB * TY * NE;        // [B,Ty,Tx]

    float* ZwT = (float*)d_ws;                                  // [B][E][Tx]
    float* Zu  = (float*)d_ws + (size_t)NB * NE * TX;           // [B][Ty][E]

    prep_kernel<<<256, dim3(64, 8), 0, stream>>>(enc, dec, Wa, Ua, ZwT, Zu);
    attn_kernel<<<512, dim3(64, 8), 0, stream>>>(enc, ZwT, Zu, Va, c_out, e_out);
}